// Round 12
// baseline (295.160 us; speedup 1.0000x reference)
//
#include <hip/hip_runtime.h>

typedef short bf16x8 __attribute__((ext_vector_type(8)));
typedef float f32x4 __attribute__((ext_vector_type(4)));
typedef unsigned int uint;
typedef unsigned short ushort;
typedef uint u32x2 __attribute__((ext_vector_type(2)));
typedef uint u32x4 __attribute__((ext_vector_type(4)));

#define NBLK 256   // edge-chunk blocks for P1/P3
#define LCAP 24576 // p4 LDS edge buffer (96 KB)
#define HP 264     // H row stride in ushorts (528B, 16B-aligned)

__device__ inline ushort f2bf(float f) {
    uint u = __builtin_bit_cast(uint, f);
    uint r = u + 0x7fffu + ((u >> 16) & 1u);  // round-to-nearest-even
    return (ushort)(r >> 16);
}
__device__ inline float bf2f(uint lo16) {
    uint u = lo16 << 16;
    return __builtin_bit_cast(float, u);
}
__device__ inline float bf2f_hi(uint v) {
    uint u = v & 0xffff0000u;
    return __builtin_bit_cast(float, u);
}

// ---------------- packw: fp32 W -> MFMA B-fragment order (ks-major), bf16 ----------------
__device__ inline void packw_body(const float* __restrict__ Wa, const float* __restrict__ Wb,
                                  ushort* __restrict__ out, int mode, int tile, int l) {
    int cb = tile >> 3, ks = tile & 7;
    int col = cb * 16 + (l & 15);
    int k0 = ks * 32 + ((l >> 4) * 8);
    ushort vals[8];
#pragma unroll
    for (int j = 0; j < 8; j++) {
        int k = k0 + j;
        float f;
        if (mode == 0)
            f = (k < 128) ? Wa[(size_t)k * 256 + col] : Wb[(size_t)(k - 128) * 256 + col];
        else
            f = (col < 128) ? Wa[(size_t)k * 128 + col] : Wb[(size_t)k * 128 + (col - 128)];
        vals[j] = f2bf(f);
    }
    ushort* dst = out + ((size_t)(ks * 16 + cb) * 64 + l) * 8;
#pragma unroll
    for (int j = 0; j < 8; j++) dst[j] = vals[j];
}

// ---------------- fused prep: p1 histogram + packw x2 + convx (slice-major) ----------------
__global__ void prep_kernel(const float* __restrict__ x, ushort* __restrict__ xsl,
                            const float* __restrict__ Wr0, const float* __restrict__ Wl0,
                            ushort* __restrict__ w1p,
                            const float* __restrict__ Wl1, const float* __restrict__ Wr1,
                            ushort* __restrict__ w2p,
                            const int* __restrict__ dst, int* __restrict__ ghist,
                            int E, int CE, int NB, int n) {
    __shared__ int hist[512];
    int bb = blockIdx.x;
    int tid = threadIdx.x;
    if (bb < NBLK) {
        for (int b = tid; b < NB; b += 256) hist[b] = 0;
        __syncthreads();
        int start = bb * CE, end = min(E, start + CE);
        for (int e = start + tid; e < end; e += 256) {
            int d = dst[e];
            atomicAdd(&hist[d >> 8], 1);
        }
        __syncthreads();
        for (int b = tid; b < NB; b += 256) ghist[(size_t)b * NBLK + bb] = hist[b];
    } else if (bb < NBLK + 64) {
        int r = bb - NBLK;
        int tile = (r & 31) * 4 + (tid >> 6);
        int l = tid & 63;
        if (r < 32) packw_body(Wr0, Wl0, w1p, 0, tile, l);
        else        packw_body(Wl1, Wr1, w2p, 1, tile, l);
    } else {
        // convx: one row per thread -> xsl[8][n][16] slice-major bf16
        int row = (bb - NBLK - 64) * 256 + tid;
        if (row < n) {
            const float* xr = x + (size_t)row * 128;
#pragma unroll
            for (int c = 0; c < 8; c++) {
                ushort h[16];
#pragma unroll
                for (int m = 0; m < 4; m++) {
                    float4 f = *(const float4*)(xr + c * 16 + m * 4);
                    h[m * 4 + 0] = f2bf(f.x); h[m * 4 + 1] = f2bf(f.y);
                    h[m * 4 + 2] = f2bf(f.z); h[m * 4 + 3] = f2bf(f.w);
                }
                ushort* dp = xsl + ((size_t)c * n + row) * 16;
                *(u32x4*)dp = *(const u32x4*)&h[0];
                *(u32x4*)(dp + 8) = *(const u32x4*)&h[8];
            }
        }
    }
}

// ---------------- hierarchical scan ----------------
__global__ void scan1_kernel(const int* __restrict__ cnt, int* __restrict__ rs,
                             int* __restrict__ bsum, int n) {
    __shared__ int tmp[256];
    int tid = threadIdx.x;
    int idx = blockIdx.x * 256 + tid;
    int v = (idx < n) ? cnt[idx] : 0;
    tmp[tid] = v;
    __syncthreads();
#pragma unroll
    for (int off = 1; off < 256; off <<= 1) {
        int t = (tid >= off) ? tmp[tid - off] : 0;
        __syncthreads();
        tmp[tid] += t;
        __syncthreads();
    }
    if (idx < n) rs[idx] = tmp[tid] - v;
    if (tid == 255) bsum[blockIdx.x] = tmp[255];
}

__global__ void scan23_kernel(int* __restrict__ rs, const int* __restrict__ bsum,
                              int n, int E) {
    __shared__ int red[256];
    int tid = threadIdx.x;
    int b = blockIdx.x;
    int s = 0;
    for (int t = tid; t < b; t += 256) s += bsum[t];
    red[tid] = s;
    __syncthreads();
#pragma unroll
    for (int off = 128; off > 0; off >>= 1) {
        if (tid < off) red[tid] += red[tid + off];
        __syncthreads();
    }
    int offv = red[0];
    int idx = b * 256 + tid;
    if (idx < n) rs[idx] += offv;
    if (b == 0 && tid == 0) rs[n] = E;
}

// P3: partition edges into bucket-major ebuck; payload = (dstLocal<<17)|src
__global__ void p3_kernel(const int* __restrict__ src, const int* __restrict__ dst,
                          const int* __restrict__ goff, uint* __restrict__ ebuck,
                          int E, int CE, int NB) {
    __shared__ int cur[512];
    int tid = threadIdx.x;
    for (int b = tid; b < NB; b += 256) cur[b] = goff[(size_t)b * NBLK + blockIdx.x];
    __syncthreads();
    int start = blockIdx.x * CE, end = min(E, start + CE);
    for (int e = start + tid; e < end; e += 256) {
        int d = dst[e];
        int s = src[e];
        int slot = atomicAdd(&cur[d >> 8], 1);
        ebuck[slot] = ((uint)(d & 255) << 17) | (uint)s;
    }
}

// P4: one block per bucket; LDS-stage slice, per-node counts, block scan -> rs, scatter nbr
__global__ void p4_kernel(const uint* __restrict__ ebuck, const int* __restrict__ goff,
                          int* __restrict__ rs, int* __restrict__ nbr, int n, int E, int NB) {
    __shared__ uint ebuf[LCAP];
    __shared__ int cnt[256];
    __shared__ int cur[256];
    int tid = threadIdx.x;
    int b = blockIdx.x;
    int d0 = b << 8;
    int eb = goff[(size_t)b * NBLK];
    int ee = (b == NB - 1) ? E : goff[(size_t)(b + 1) * NBLK];
    cnt[tid] = 0;
    __syncthreads();
    int m = ee - eb;
    for (int i = tid; i < m; i += 256) {
        uint v = ebuck[eb + i];
        if (i < LCAP) ebuf[i] = v;
        atomicAdd(&cnt[v >> 17], 1);
    }
    __syncthreads();
    int v0 = cnt[tid];
    cur[tid] = v0;
    __syncthreads();
#pragma unroll
    for (int off = 1; off < 256; off <<= 1) {
        int t = (tid >= off) ? cur[tid - off] : 0;
        __syncthreads();
        cur[tid] += t;
        __syncthreads();
    }
    int excl = cur[tid] - v0;
    int node = d0 + tid;
    if (node < n) rs[node] = eb + excl;
    if (b == NB - 1 && tid == 0) rs[n] = E;
    __syncthreads();
    cur[tid] = eb + excl;
    __syncthreads();
    for (int i = tid; i < m; i += 256) {
        uint v = (i < LCAP) ? ebuf[i] : ebuck[eb + i];
        int p = atomicAdd(&cur[v >> 17], 1);
        nbr[p] = (int)(v & 0x1FFFFu);
    }
}

// ---------------- fused 2-layer MFMA GEMM: register-B, column-split waves ----------------
// Same validated structure as R11; A-tile staged from slice-major xb/agg tables,
// z emitted slice-major.
__launch_bounds__(512, 1)
__global__ void fused_gemm_kernel(const ushort* __restrict__ xsl, const ushort* __restrict__ asl,
                                  const ushort* __restrict__ W1, const ushort* __restrict__ W2,
                                  const float* __restrict__ b0, const float* __restrict__ b1,
                                  ushort* __restrict__ zsl, float* __restrict__ outf, int n) {
    extern __shared__ ushort H[];  // [128][HP]
    int tid = threadIdx.x;
    int l = tid & 63, w = tid >> 6;  // 8 waves
    int q = l >> 4, r16 = l & 15;
    int row0 = blockIdx.x * 128;

    // ---- stage A1 tile -> H from slice-major tables (16 slices x 4KB contiguous) ----
    {
        int row = tid >> 2;        // 0..127
        int ql = tid & 3;
        int grow = row0 + row;
        if (grow > n - 1) grow = n - 1;
#pragma unroll
        for (int s = 0; s < 16; s++) {
            const ushort* src = (s < 8) ? (xsl + ((size_t)s * n + grow) * 16)
                                        : (asl + ((size_t)(s - 8) * n + grow) * 16);
            uint2 v = *(const uint2*)(src + ql * 4);
            *(uint2*)(&H[(size_t)row * HP + s * 16 + ql * 4]) = v;
        }
    }

    // ---- layer-1 B fragments for this wave's cb pair ----
    bf16x8 bf1[2][8];
#pragma unroll
    for (int cbi = 0; cbi < 2; cbi++) {
        int cb = 2 * w + cbi;
#pragma unroll
        for (int ks = 0; ks < 8; ks++)
            bf1[cbi][ks] = *(const bf16x8*)(W1 + ((size_t)((ks * 16 + cb) * 64 + l)) * 8);
    }

    f32x4 acc[8][2];
#pragma unroll
    for (int rg = 0; rg < 8; rg++)
#pragma unroll
        for (int cbi = 0; cbi < 2; cbi++) acc[rg][cbi] = (f32x4){0.f, 0.f, 0.f, 0.f};

    __syncthreads();  // A1 tile staged

    // ================= layer 1 =================
#pragma unroll
    for (int rg = 0; rg < 8; rg++) {
        bf16x8 a[8];
        const ushort* hp = &H[(size_t)(rg * 16 + r16) * HP + q * 8];
#pragma unroll
        for (int ks = 0; ks < 8; ks++) a[ks] = *(const bf16x8*)(hp + ks * 32);
#pragma unroll
        for (int cbi = 0; cbi < 2; cbi++)
#pragma unroll
            for (int ks = 0; ks < 8; ks++)
                acc[rg][cbi] = __builtin_amdgcn_mfma_f32_16x16x32_bf16(bf1[cbi][ks], a[ks],
                                                                       acc[rg][cbi], 0, 0, 0);
    }

    // prefetch layer-2 B frags
    bf16x8 bf2[2][8];
#pragma unroll
    for (int cbi = 0; cbi < 2; cbi++) {
        int cb = 2 * w + cbi;
#pragma unroll
        for (int ks = 0; ks < 8; ks++)
            bf2[cbi][ks] = *(const bf16x8*)(W2 + ((size_t)((ks * 16 + cb) * 64 + l)) * 8);
    }

    __syncthreads();  // all A1 reads done; safe to overwrite H with h

    // ---- epilogue 1: h = relu(acc + b0) -> H column slice [32w, 32w+32) ----
#pragma unroll
    for (int rg = 0; rg < 8; rg++) {
#pragma unroll
        for (int cbi = 0; cbi < 2; cbi++) {
            int colb = (2 * w + cbi) * 16 + q * 4;
            f32x4 bv = *(const f32x4*)(b0 + colb);
            f32x4 v = acc[rg][cbi];
            float v0 = fmaxf(v[0] + bv[0], 0.f);
            float v1 = fmaxf(v[1] + bv[1], 0.f);
            float v2 = fmaxf(v[2] + bv[2], 0.f);
            float v3 = fmaxf(v[3] + bv[3], 0.f);
            u32x2 pk;
            pk[0] = (uint)f2bf(v0) | ((uint)f2bf(v1) << 16);
            pk[1] = (uint)f2bf(v2) | ((uint)f2bf(v3) << 16);
            *(u32x2*)(&H[(size_t)(rg * 16 + r16) * HP + colb]) = pk;
            acc[rg][cbi] = (f32x4){0.f, 0.f, 0.f, 0.f};
        }
    }

    __syncthreads();  // h complete

    // ================= layer 2 =================
#pragma unroll
    for (int rg = 0; rg < 8; rg++) {
        bf16x8 a[8];
        const ushort* hp = &H[(size_t)(rg * 16 + r16) * HP + q * 8];
#pragma unroll
        for (int ks = 0; ks < 8; ks++) a[ks] = *(const bf16x8*)(hp + ks * 32);
#pragma unroll
        for (int cbi = 0; cbi < 2; cbi++)
#pragma unroll
            for (int ks = 0; ks < 8; ks++)
                acc[rg][cbi] = __builtin_amdgcn_mfma_f32_16x16x32_bf16(bf2[cbi][ks], a[ks],
                                                                       acc[rg][cbi], 0, 0, 0);
    }

    // ---- epilogue 2: DIRECT global stores ----
    if (w < 4) {
        // z slices {2w, 2w+1}: slice-major [8][n][16]; 16 rows x 32B contiguous per frag
#pragma unroll
        for (int rg = 0; rg < 8; rg++) {
            int row = row0 + rg * 16 + r16;
#pragma unroll
            for (int cbi = 0; cbi < 2; cbi++) {
                int slice = 2 * w + cbi;
                f32x4 v = acc[rg][cbi];
                u32x2 pk;
                pk[0] = (uint)f2bf(v[0]) | ((uint)f2bf(v[1]) << 16);
                pk[1] = (uint)f2bf(v[2]) | ((uint)f2bf(v[3]) << 16);
                if (row < n)
                    *(u32x2*)(zsl + ((size_t)slice * n + row) * 16 + q * 4) = pk;
            }
        }
    } else {
        int wq = w - 4;
#pragma unroll
        for (int rg = 0; rg < 8; rg++) {
            int row = row0 + rg * 16 + r16;
#pragma unroll
            for (int cbi = 0; cbi < 2; cbi++) {
                int colb = 32 * wq + cbi * 16 + q * 4;
                f32x4 bv = *(const f32x4*)(b1 + colb);
                f32x4 v = acc[rg][cbi];
                v[0] += bv[0]; v[1] += bv[1]; v[2] += bv[2]; v[3] += bv[3];
                if (row < n)
                    *(f32x4*)(outf + (size_t)row * 128 + colb) = v;
            }
        }
    }
}

// ---------------- segment mean, XCD-local slices ----------------
// Grid: (slice c = blockIdx&7, node chunk = blockIdx>>3). Block 256 thr = 64 quads = 64 nodes.
// Quad lane ql owns features c*16 + ql*4 .. +3 (8B per edge row). Slice table = 3.2MB,
// L2-resident on its XCD (round-robin block->XCD dispatch).
// ADD=0: out -> agg_sl[c][i][16] bf16.  ADD=1: outf[i*128 + c*16 + ql*4] += (f32x4 RMW).
template <int ADD>
__global__ void segmean_kernel(const ushort* __restrict__ tbl, const int* __restrict__ rs,
                               const int* __restrict__ nbr, ushort* __restrict__ outb,
                               float* __restrict__ outf, int n) {
    int tid = threadIdx.x;
    int c = blockIdx.x & 7;
    int i = (blockIdx.x >> 3) * 64 + (tid >> 2);
    if (i >= n) return;
    int ql = tid & 3;
    int b = rs[i], e = rs[i + 1];
    const ushort* tb = tbl + ((size_t)c * n) * 16 + ql * 4;
    float a0 = 0.f, a1 = 0.f, a2 = 0.f, a3 = 0.f;
    int j = b;
    for (; j + 4 <= e; j += 4) {
        int s0 = nbr[j], s1 = nbr[j + 1], s2 = nbr[j + 2], s3 = nbr[j + 3];
        uint2 v0 = *(const uint2*)(tb + (size_t)s0 * 16);
        uint2 v1 = *(const uint2*)(tb + (size_t)s1 * 16);
        uint2 v2 = *(const uint2*)(tb + (size_t)s2 * 16);
        uint2 v3 = *(const uint2*)(tb + (size_t)s3 * 16);
        a0 += bf2f(v0.x & 0xffffu) + bf2f(v1.x & 0xffffu) + bf2f(v2.x & 0xffffu) + bf2f(v3.x & 0xffffu);
        a1 += bf2f_hi(v0.x) + bf2f_hi(v1.x) + bf2f_hi(v2.x) + bf2f_hi(v3.x);
        a2 += bf2f(v0.y & 0xffffu) + bf2f(v1.y & 0xffffu) + bf2f(v2.y & 0xffffu) + bf2f(v3.y & 0xffffu);
        a3 += bf2f_hi(v0.y) + bf2f_hi(v1.y) + bf2f_hi(v2.y) + bf2f_hi(v3.y);
    }
    for (; j < e; j++) {
        uint2 v = *(const uint2*)(tb + (size_t)nbr[j] * 16);
        a0 += bf2f(v.x & 0xffffu);
        a1 += bf2f_hi(v.x);
        a2 += bf2f(v.y & 0xffffu);
        a3 += bf2f_hi(v.y);
    }
    int dg = e - b;
    float inv = 1.0f / (float)(dg > 1 ? dg : 1);
    a0 *= inv; a1 *= inv; a2 *= inv; a3 *= inv;
    if (ADD) {
        float* op = outf + (size_t)i * 128 + c * 16 + ql * 4;
        f32x4 o = *(const f32x4*)op;
        o[0] += a0; o[1] += a1; o[2] += a2; o[3] += a3;
        *(f32x4*)op = o;
    } else {
        u32x2 pk;
        pk[0] = (uint)f2bf(a0) | ((uint)f2bf(a1) << 16);
        pk[1] = (uint)f2bf(a2) | ((uint)f2bf(a3) << 16);
        *(u32x2*)(outb + ((size_t)c * n + i) * 16 + ql * 4) = pk;
    }
}

// ---------------- launch ----------------

extern "C" void kernel_launch(void* const* d_in, const int* in_sizes, int n_in,
                              void* d_out, int out_size, void* d_ws, size_t ws_size,
                              hipStream_t stream) {
    const float* x = (const float*)d_in[0];
    const int* ei = (const int*)d_in[1];
    const float* Wl0 = (const float*)d_in[2];
    const float* bl0 = (const float*)d_in[3];
    const float* Wr0 = (const float*)d_in[4];
    const float* Wl1 = (const float*)d_in[5];
    const float* bl1 = (const float*)d_in[6];
    const float* Wr1 = (const float*)d_in[7];
    float* outp = (float*)d_out;

    int n = in_sizes[0] / 128;  // 100000
    int E = in_sizes[1] / 2;    // 1600000
    const int* srcv = ei;
    const int* dstv = ei + E;

    int NB = (n + 255) >> 8;
    int NG = NB * NBLK;
    int CE = (E + NBLK - 1) / NBLK;

    char* w = (char*)d_ws;
    auto align = [](size_t v) { return (v + 255) & ~(size_t)255; };
    size_t off = 0;
    int* rs    = (int*)(w + off); off = align(off + (size_t)(n + 1) * 4);
    int* bsum2 = (int*)(w + off); off = align(off + (size_t)512 * 4);
    int* ghist = (int*)(w + off); off = align(off + (size_t)(NG + 1) * 4);
    int* goff  = (int*)(w + off); off = align(off + (size_t)(NG + 1) * 4);
    uint* ebuck = (uint*)(w + off); off = align(off + (size_t)E * 4);
    int* nbr   = (int*)(w + off); off = align(off + (size_t)E * 4);
    ushort* xsl = (ushort*)(w + off); off = align(off + (size_t)n * 128 * 2);  // [8][n][16]
    ushort* asl = (ushort*)(w + off); off = align(off + (size_t)n * 128 * 2);  // [8][n][16]
    ushort* zsl = (ushort*)(w + off); off = align(off + (size_t)n * 128 * 2);  // [8][n][16]
    ushort* w1p = (ushort*)(w + off); off = align(off + (size_t)256 * 256 * 2);
    ushort* w2p = (ushort*)(w + off); off = align(off + (size_t)256 * 256 * 2);
    (void)ws_size; (void)n_in; (void)out_size;

    int nb2 = (NG + 255) / 256;
    int ncx = (n + 255) / 256;  // convx blocks (one row per thread)

    // CSR build + conversions
    prep_kernel<<<NBLK + 64 + ncx, 256, 0, stream>>>(x, xsl, Wr0, Wl0, w1p, Wl1, Wr1, w2p,
                                                     dstv, ghist, E, CE, NB, n);
    scan1_kernel<<<nb2, 256, 0, stream>>>(ghist, goff, bsum2, NG);
    scan23_kernel<<<nb2, 256, 0, stream>>>(goff, bsum2, NG, E);
    p3_kernel<<<NBLK, 256, 0, stream>>>(srcv, dstv, goff, ebuck, E, CE, NB);
    p4_kernel<<<NB, 256, 0, stream>>>(ebuck, goff, rs, nbr, n, E, NB);

    int segb = ((n + 63) / 64) * 8;  // (node-chunk, slice) pairs
    int mb = (n + 127) / 128;
    int ldsz = 128 * HP * 2;  // 67584

    hipFuncSetAttribute((const void*)fused_gemm_kernel,
                        hipFuncAttributeMaxDynamicSharedMemorySize, ldsz);

    // layer 1 gather (slice-local), fused 2-layer GEMM, layer 2 gather (slice-local)
    segmean_kernel<0><<<segb, 256, 0, stream>>>(xsl, rs, nbr, asl, nullptr, n);
    fused_gemm_kernel<<<mb, 512, ldsz, stream>>>(xsl, asl, w1p, w2p, bl0, bl1, zsl, outp, n);
    segmean_kernel<1><<<segb, 256, 0, stream>>>(zsl, rs, nbr, nullptr, outp, n);
}

// Round 13
// 248.472 us; speedup vs baseline: 1.1879x; 1.1879x over previous
//
#include <hip/hip_runtime.h>

typedef short bf16x8 __attribute__((ext_vector_type(8)));
typedef float f32x4 __attribute__((ext_vector_type(4)));
typedef unsigned int uint;
typedef unsigned short ushort;
typedef uint u32x2 __attribute__((ext_vector_type(2)));
typedef uint u32x4 __attribute__((ext_vector_type(4)));

#define NBLK 256   // edge-chunk blocks for P1/P3
#define LCAP 24576 // p4 LDS edge buffer (96 KB)
#define HP 264     // H row stride in ushorts (528B, 16B-aligned)

__device__ inline ushort f2bf(float f) {
    uint u = __builtin_bit_cast(uint, f);
    uint r = u + 0x7fffu + ((u >> 16) & 1u);  // round-to-nearest-even
    return (ushort)(r >> 16);
}
__device__ inline float bf2f(uint lo16) {
    uint u = lo16 << 16;
    return __builtin_bit_cast(float, u);
}
__device__ inline float bf2f_hi(uint v) {
    uint u = v & 0xffff0000u;
    return __builtin_bit_cast(float, u);
}

// ---------------- packw: fp32 W -> MFMA B-fragment order (ks-major), bf16 ----------------
__device__ inline void packw_body(const float* __restrict__ Wa, const float* __restrict__ Wb,
                                  ushort* __restrict__ out, int mode, int tile, int l) {
    int cb = tile >> 3, ks = tile & 7;
    int col = cb * 16 + (l & 15);
    int k0 = ks * 32 + ((l >> 4) * 8);
    ushort vals[8];
#pragma unroll
    for (int j = 0; j < 8; j++) {
        int k = k0 + j;
        float f;
        if (mode == 0)
            f = (k < 128) ? Wa[(size_t)k * 256 + col] : Wb[(size_t)(k - 128) * 256 + col];
        else
            f = (col < 128) ? Wa[(size_t)k * 128 + col] : Wb[(size_t)k * 128 + (col - 128)];
        vals[j] = f2bf(f);
    }
    ushort* dst = out + ((size_t)(ks * 16 + cb) * 64 + l) * 8;
#pragma unroll
    for (int j = 0; j < 8; j++) dst[j] = vals[j];
}

// ---------------- fused prep: p1 histogram + packw x2 + convx ----------------
__global__ void prep_kernel(const float* __restrict__ x, ushort* __restrict__ a1,
                            const float* __restrict__ Wr0, const float* __restrict__ Wl0,
                            ushort* __restrict__ w1p,
                            const float* __restrict__ Wl1, const float* __restrict__ Wr1,
                            ushort* __restrict__ w2p,
                            const int* __restrict__ dst, int* __restrict__ ghist,
                            int E, int CE, int NB, int n) {
    __shared__ int hist[512];
    int bb = blockIdx.x;
    int tid = threadIdx.x;
    if (bb < NBLK) {
        for (int b = tid; b < NB; b += 256) hist[b] = 0;
        __syncthreads();
        int start = bb * CE, end = min(E, start + CE);
        for (int e = start + tid; e < end; e += 256) {
            int d = dst[e];
            atomicAdd(&hist[d >> 8], 1);
        }
        __syncthreads();
        for (int b = tid; b < NB; b += 256) ghist[(size_t)b * NBLK + bb] = hist[b];
    } else if (bb < NBLK + 64) {
        int r = bb - NBLK;
        int tile = (r & 31) * 4 + (tid >> 6);
        int l = tid & 63;
        if (r < 32) packw_body(Wr0, Wl0, w1p, 0, tile, l);
        else        packw_body(Wl1, Wr1, w2p, 1, tile, l);
    } else {
        int i = (bb - NBLK - 64) * 256 + tid;
        int total = n * 32;
        if (i < total) {
            int row = i >> 5, q = i & 31;
            float4 v = *(const float4*)(x + (size_t)row * 128 + q * 4);
            ushort4 o;
            o.x = f2bf(v.x); o.y = f2bf(v.y); o.z = f2bf(v.z); o.w = f2bf(v.w);
            *(ushort4*)(a1 + (size_t)row * 256 + q * 4) = o;
        }
    }
}

// ---------------- hierarchical scan ----------------
__global__ void scan1_kernel(const int* __restrict__ cnt, int* __restrict__ rs,
                             int* __restrict__ bsum, int n) {
    __shared__ int tmp[256];
    int tid = threadIdx.x;
    int idx = blockIdx.x * 256 + tid;
    int v = (idx < n) ? cnt[idx] : 0;
    tmp[tid] = v;
    __syncthreads();
#pragma unroll
    for (int off = 1; off < 256; off <<= 1) {
        int t = (tid >= off) ? tmp[tid - off] : 0;
        __syncthreads();
        tmp[tid] += t;
        __syncthreads();
    }
    if (idx < n) rs[idx] = tmp[tid] - v;
    if (tid == 255) bsum[blockIdx.x] = tmp[255];
}

__global__ void scan23_kernel(int* __restrict__ rs, const int* __restrict__ bsum,
                              int n, int E) {
    __shared__ int red[256];
    int tid = threadIdx.x;
    int b = blockIdx.x;
    int s = 0;
    for (int t = tid; t < b; t += 256) s += bsum[t];
    red[tid] = s;
    __syncthreads();
#pragma unroll
    for (int off = 128; off > 0; off >>= 1) {
        if (tid < off) red[tid] += red[tid + off];
        __syncthreads();
    }
    int offv = red[0];
    int idx = b * 256 + tid;
    if (idx < n) rs[idx] += offv;
    if (b == 0 && tid == 0) rs[n] = E;
}

// P3: partition edges into bucket-major ebuck; payload = (dstLocal<<17)|src
__global__ void p3_kernel(const int* __restrict__ src, const int* __restrict__ dst,
                          const int* __restrict__ goff, uint* __restrict__ ebuck,
                          int E, int CE, int NB) {
    __shared__ int cur[512];
    int tid = threadIdx.x;
    for (int b = tid; b < NB; b += 256) cur[b] = goff[(size_t)b * NBLK + blockIdx.x];
    __syncthreads();
    int start = blockIdx.x * CE, end = min(E, start + CE);
    for (int e = start + tid; e < end; e += 256) {
        int d = dst[e];
        int s = src[e];
        int slot = atomicAdd(&cur[d >> 8], 1);
        ebuck[slot] = ((uint)(d & 255) << 17) | (uint)s;
    }
}

// P4: one block per bucket; LDS-stage slice, per-node counts, block scan -> rs, scatter nbr
__global__ void p4_kernel(const uint* __restrict__ ebuck, const int* __restrict__ goff,
                          int* __restrict__ rs, int* __restrict__ nbr, int n, int E, int NB) {
    __shared__ uint ebuf[LCAP];
    __shared__ int cnt[256];
    __shared__ int cur[256];
    int tid = threadIdx.x;
    int b = blockIdx.x;
    int d0 = b << 8;
    int eb = goff[(size_t)b * NBLK];
    int ee = (b == NB - 1) ? E : goff[(size_t)(b + 1) * NBLK];
    cnt[tid] = 0;
    __syncthreads();
    int m = ee - eb;
    for (int i = tid; i < m; i += 256) {
        uint v = ebuck[eb + i];
        if (i < LCAP) ebuf[i] = v;
        atomicAdd(&cnt[v >> 17], 1);
    }
    __syncthreads();
    int v0 = cnt[tid];
    cur[tid] = v0;
    __syncthreads();
#pragma unroll
    for (int off = 1; off < 256; off <<= 1) {
        int t = (tid >= off) ? cur[tid - off] : 0;
        __syncthreads();
        cur[tid] += t;
        __syncthreads();
    }
    int excl = cur[tid] - v0;
    int node = d0 + tid;
    if (node < n) rs[node] = eb + excl;
    if (b == NB - 1 && tid == 0) rs[n] = E;
    __syncthreads();
    cur[tid] = eb + excl;
    __syncthreads();
    for (int i = tid; i < m; i += 256) {
        uint v = (i < LCAP) ? ebuf[i] : ebuck[eb + i];
        int p = atomicAdd(&cur[v >> 17], 1);
        nbr[p] = (int)(v & 0x1FFFFu);
    }
}

// ---------------- fused 2-layer MFMA GEMM: register-B, column-split waves ----------------
// Block = 128 rows, 8 waves. Wave w owns cols [32w, 32w+32) for ALL 128 rows of both
// layers; B-frags in VGPRs. LDS H[128][HP]: A1 tile, then h. All transitions fenced.
// Epilogue-2: cols 0..127 -> zb (bf16); cols 128..255 -> sb (bf16 self-term, +b1).
__launch_bounds__(512, 1)
__global__ void fused_gemm_kernel(const ushort* __restrict__ A, const ushort* __restrict__ W1,
                                  const ushort* __restrict__ W2, const float* __restrict__ b0,
                                  const float* __restrict__ b1, ushort* __restrict__ zb,
                                  ushort* __restrict__ sb, int n) {
    extern __shared__ ushort H[];  // [128][HP]
    int tid = threadIdx.x;
    int l = tid & 63, w = tid >> 6;  // 8 waves
    int q = l >> 4, r16 = l & 15;
    int row0 = blockIdx.x * 128;

    // ---- stage A1 tile -> H (cooperative; 32 lanes = one 512B row) ----
    {
        int rr = tid >> 5;          // 0..15
        int cc = (tid & 31) * 8;    // ushort col
#pragma unroll
        for (int it = 0; it < 8; it++) {
            int lr = it * 16 + rr;
            int row = row0 + lr;
            if (row > n - 1) row = n - 1;
            u32x4 v = *(const u32x4*)(A + (size_t)row * 256 + cc);
            *(u32x4*)(&H[(size_t)lr * HP + cc]) = v;
        }
    }

    // ---- layer-1 B fragments for this wave's cb pair ----
    bf16x8 bf1[2][8];
#pragma unroll
    for (int cbi = 0; cbi < 2; cbi++) {
        int cb = 2 * w + cbi;
#pragma unroll
        for (int ks = 0; ks < 8; ks++)
            bf1[cbi][ks] = *(const bf16x8*)(W1 + ((size_t)((ks * 16 + cb) * 64 + l)) * 8);
    }

    f32x4 acc[8][2];
#pragma unroll
    for (int rg = 0; rg < 8; rg++)
#pragma unroll
        for (int cbi = 0; cbi < 2; cbi++) acc[rg][cbi] = (f32x4){0.f, 0.f, 0.f, 0.f};

    __syncthreads();  // A1 tile staged

    // ================= layer 1 =================
#pragma unroll
    for (int rg = 0; rg < 8; rg++) {
        bf16x8 a[8];
        const ushort* hp = &H[(size_t)(rg * 16 + r16) * HP + q * 8];
#pragma unroll
        for (int ks = 0; ks < 8; ks++) a[ks] = *(const bf16x8*)(hp + ks * 32);
#pragma unroll
        for (int cbi = 0; cbi < 2; cbi++)
#pragma unroll
            for (int ks = 0; ks < 8; ks++)
                acc[rg][cbi] = __builtin_amdgcn_mfma_f32_16x16x32_bf16(bf1[cbi][ks], a[ks],
                                                                       acc[rg][cbi], 0, 0, 0);
    }

    // prefetch layer-2 B frags
    bf16x8 bf2[2][8];
#pragma unroll
    for (int cbi = 0; cbi < 2; cbi++) {
        int cb = 2 * w + cbi;
#pragma unroll
        for (int ks = 0; ks < 8; ks++)
            bf2[cbi][ks] = *(const bf16x8*)(W2 + ((size_t)((ks * 16 + cb) * 64 + l)) * 8);
    }

    __syncthreads();  // all A1 reads done; safe to overwrite H with h

    // ---- epilogue 1: h = relu(acc + b0) -> H column slice [32w, 32w+32) ----
#pragma unroll
    for (int rg = 0; rg < 8; rg++) {
#pragma unroll
        for (int cbi = 0; cbi < 2; cbi++) {
            int colb = (2 * w + cbi) * 16 + q * 4;
            f32x4 bv = *(const f32x4*)(b0 + colb);
            f32x4 v = acc[rg][cbi];
            float v0 = fmaxf(v[0] + bv[0], 0.f);
            float v1 = fmaxf(v[1] + bv[1], 0.f);
            float v2 = fmaxf(v[2] + bv[2], 0.f);
            float v3 = fmaxf(v[3] + bv[3], 0.f);
            u32x2 pk;
            pk[0] = (uint)f2bf(v0) | ((uint)f2bf(v1) << 16);
            pk[1] = (uint)f2bf(v2) | ((uint)f2bf(v3) << 16);
            *(u32x2*)(&H[(size_t)(rg * 16 + r16) * HP + colb]) = pk;
            acc[rg][cbi] = (f32x4){0.f, 0.f, 0.f, 0.f};
        }
    }

    __syncthreads();  // h complete

    // ================= layer 2 =================
#pragma unroll
    for (int rg = 0; rg < 8; rg++) {
        bf16x8 a[8];
        const ushort* hp = &H[(size_t)(rg * 16 + r16) * HP + q * 8];
#pragma unroll
        for (int ks = 0; ks < 8; ks++) a[ks] = *(const bf16x8*)(hp + ks * 32);
#pragma unroll
        for (int cbi = 0; cbi < 2; cbi++)
#pragma unroll
            for (int ks = 0; ks < 8; ks++)
                acc[rg][cbi] = __builtin_amdgcn_mfma_f32_16x16x32_bf16(bf2[cbi][ks], a[ks],
                                                                       acc[rg][cbi], 0, 0, 0);
    }

    // ---- epilogue 2: DIRECT global stores (bf16 both halves) ----
    if (w < 4) {
        // cols [32w, 32w+32) of zb (bf16)
#pragma unroll
        for (int rg = 0; rg < 8; rg++) {
            int row = row0 + rg * 16 + r16;
#pragma unroll
            for (int cbi = 0; cbi < 2; cbi++) {
                int colb = (2 * w + cbi) * 16 + q * 4;
                f32x4 v = acc[rg][cbi];
                u32x2 pk;
                pk[0] = (uint)f2bf(v[0]) | ((uint)f2bf(v[1]) << 16);
                pk[1] = (uint)f2bf(v[2]) | ((uint)f2bf(v[3]) << 16);
                if (row < n)
                    *(u32x2*)(zb + (size_t)row * 128 + colb) = pk;
            }
        }
    } else {
        // cols [32(w-4), +32) of sb = bf16(self + b1)
        int wq = w - 4;
#pragma unroll
        for (int rg = 0; rg < 8; rg++) {
            int row = row0 + rg * 16 + r16;
#pragma unroll
            for (int cbi = 0; cbi < 2; cbi++) {
                int colb = 32 * wq + cbi * 16 + q * 4;
                f32x4 bv = *(const f32x4*)(b1 + colb);
                f32x4 v = acc[rg][cbi];
                v[0] += bv[0]; v[1] += bv[1]; v[2] += bv[2]; v[3] += bv[3];
                u32x2 pk;
                pk[0] = (uint)f2bf(v[0]) | ((uint)f2bf(v[1]) << 16);
                pk[1] = (uint)f2bf(v[2]) | ((uint)f2bf(v[3]) << 16);
                if (row < n)
                    *(u32x2*)(sb + (size_t)row * 128 + colb) = pk;
            }
        }
    }
}

// ---------------- segment mean: 2 rows per load instruction (R11-validated) ----------------
// ADD=0: outb[i*half + ...] = packed bf16 mean
// ADD=1: outf[i*128 + ...] = bf2f(sb[i*128 + ...]) + mean   (self-term + aggregate)
template <int ADD>
__global__ void segmean_kernel(const uint* __restrict__ fp, int half,
                               const int* __restrict__ rs, const int* __restrict__ nbr,
                               uint* __restrict__ outb, float* __restrict__ outf,
                               const ushort* __restrict__ sb, int n) {
    int w = threadIdx.x >> 6;
    int l = threadIdx.x & 63;
    int i = blockIdx.x * 4 + w;
    if (i >= n) return;
    int b = rs[i], e = rs[i + 1];
    int q = l & 31;
    int hsel = l >> 5;
    int stride2 = half >> 1;
    const uint2* fpq = (const uint2*)fp + q;
    float a0 = 0.f, a1 = 0.f, a2 = 0.f, a3 = 0.f;
    int j = b;
    for (; j + 8 <= e; j += 8) {
        int s[4];
#pragma unroll
        for (int p = 0; p < 4; p++) s[p] = nbr[j + 2 * p + hsel];
        uint2 v[4];
#pragma unroll
        for (int p = 0; p < 4; p++) v[p] = fpq[(size_t)s[p] * stride2];
#pragma unroll
        for (int p = 0; p < 4; p++) {
            a0 += bf2f(v[p].x & 0xffffu); a1 += bf2f_hi(v[p].x);
            a2 += bf2f(v[p].y & 0xffffu); a3 += bf2f_hi(v[p].y);
        }
    }
    for (; j + 2 <= e; j += 2) {
        int s = nbr[j + hsel];
        uint2 v = fpq[(size_t)s * stride2];
        a0 += bf2f(v.x & 0xffffu); a1 += bf2f_hi(v.x);
        a2 += bf2f(v.y & 0xffffu); a3 += bf2f_hi(v.y);
    }
    if (j < e && hsel == 0) {
        int s = nbr[j];
        uint2 v = fpq[(size_t)s * stride2];
        a0 += bf2f(v.x & 0xffffu); a1 += bf2f_hi(v.x);
        a2 += bf2f(v.y & 0xffffu); a3 += bf2f_hi(v.y);
    }
    a0 += __shfl_xor(a0, 32);
    a1 += __shfl_xor(a1, 32);
    a2 += __shfl_xor(a2, 32);
    a3 += __shfl_xor(a3, 32);
    if (hsel == 0) {
        int dg = e - b;
        float inv = 1.0f / (float)(dg > 1 ? dg : 1);
        a0 *= inv; a1 *= inv; a2 *= inv; a3 *= inv;
        if (ADD) {
            uint2 sv = *(const uint2*)(sb + (size_t)i * 128 + q * 4);
            f32x4 o;
            o[0] = bf2f(sv.x & 0xffffu) + a0;
            o[1] = bf2f_hi(sv.x) + a1;
            o[2] = bf2f(sv.y & 0xffffu) + a2;
            o[3] = bf2f_hi(sv.y) + a3;
            *(f32x4*)(outf + (size_t)i * 128 + q * 4) = o;
        } else {
            u32x2 pk;
            pk[0] = (uint)f2bf(a0) | ((uint)f2bf(a1) << 16);
            pk[1] = (uint)f2bf(a2) | ((uint)f2bf(a3) << 16);
            *(u32x2*)(outb + (size_t)i * half + q * 2) = pk;
        }
    }
}

// ---------------- launch ----------------

extern "C" void kernel_launch(void* const* d_in, const int* in_sizes, int n_in,
                              void* d_out, int out_size, void* d_ws, size_t ws_size,
                              hipStream_t stream) {
    const float* x = (const float*)d_in[0];
    const int* ei = (const int*)d_in[1];
    const float* Wl0 = (const float*)d_in[2];
    const float* bl0 = (const float*)d_in[3];
    const float* Wr0 = (const float*)d_in[4];
    const float* Wl1 = (const float*)d_in[5];
    const float* bl1 = (const float*)d_in[6];
    const float* Wr1 = (const float*)d_in[7];
    float* outp = (float*)d_out;

    int n = in_sizes[0] / 128;  // 100000
    int E = in_sizes[1] / 2;    // 1600000
    const int* srcv = ei;
    const int* dstv = ei + E;

    int NB = (n + 255) >> 8;
    int NG = NB * NBLK;
    int CE = (E + NBLK - 1) / NBLK;

    char* w = (char*)d_ws;
    auto align = [](size_t v) { return (v + 255) & ~(size_t)255; };
    size_t off = 0;
    int* rs    = (int*)(w + off); off = align(off + (size_t)(n + 1) * 4);
    int* bsum2 = (int*)(w + off); off = align(off + (size_t)512 * 4);
    int* ghist = (int*)(w + off); off = align(off + (size_t)(NG + 1) * 4);
    int* goff  = (int*)(w + off); off = align(off + (size_t)(NG + 1) * 4);
    uint* ebuck = (uint*)(w + off); off = align(off + (size_t)E * 4);
    int* nbr   = (int*)(w + off); off = align(off + (size_t)E * 4);
    ushort* a1  = (ushort*)(w + off); off = align(off + (size_t)n * 256 * 2);  // [xb | aggb]
    ushort* zb  = (ushort*)(w + off); off = align(off + (size_t)n * 128 * 2);
    ushort* sbf = (ushort*)(w + off); off = align(off + (size_t)n * 128 * 2);  // bf16 self-term
    ushort* w1p = (ushort*)(w + off); off = align(off + (size_t)256 * 256 * 2);
    ushort* w2p = (ushort*)(w + off); off = align(off + (size_t)256 * 256 * 2);
    (void)ws_size; (void)n_in; (void)out_size;

    int nb2 = (NG + 255) / 256;
    int ncx = (n * 32 + 255) / 256;

    // CSR build + conversions
    prep_kernel<<<NBLK + 64 + ncx, 256, 0, stream>>>(x, a1, Wr0, Wl0, w1p, Wl1, Wr1, w2p,
                                                     dstv, ghist, E, CE, NB, n);
    scan1_kernel<<<nb2, 256, 0, stream>>>(ghist, goff, bsum2, NG);
    scan23_kernel<<<nb2, 256, 0, stream>>>(goff, bsum2, NG, E);
    p3_kernel<<<NBLK, 256, 0, stream>>>(srcv, dstv, goff, ebuck, E, CE, NB);
    p4_kernel<<<NB, 256, 0, stream>>>(ebuck, goff, rs, nbr, n, E, NB);

    int segb = (n + 3) / 4;
    int mb = (n + 127) / 128;
    int ldsz = 128 * HP * 2;  // 67584

    hipFuncSetAttribute((const void*)fused_gemm_kernel,
                        hipFuncAttributeMaxDynamicSharedMemorySize, ldsz);

    // layer 1 gather, fused 2-layer GEMM (h in LDS; self-term bf16), layer 2 gather+combine
    segmean_kernel<0><<<segb, 256, 0, stream>>>((const uint*)a1, 128, rs, nbr,
                                                (uint*)(a1 + 128), nullptr, nullptr, n);
    fused_gemm_kernel<<<mb, 512, ldsz, stream>>>(a1, w1p, w2p, bl0, bl1, zb, sbf, n);
    segmean_kernel<1><<<segb, 256, 0, stream>>>((const uint*)zb, 64, rs, nbr,
                                                nullptr, outp, sbf, n);
}